// Round 4
// baseline (1057.981 us; speedup 1.0000x reference)
//
#include <hip/hip_runtime.h>
#include <hip/hip_bf16.h>

#define N_NODES 50000
#define N_EDGES 800000
#define D 128
#define NLAYERS 4
#define N_GRAPHS 512
#define N_CLASSES 10
#define BN_EPS 1e-5f
#define SCAN_BLOCKS ((N_NODES + 1023) / 1024)

// ---------------- CSR build ----------------
__global__ void k_hist(const int* __restrict__ ei, int* __restrict__ counts) {
    int e = blockIdx.x * blockDim.x + threadIdx.x;
    if (e < N_EDGES) atomicAdd(&counts[ei[N_EDGES + e]], 1);
}

// per-1024-block inclusive scan; also deg_inv = rsqrt(count+1)
__global__ __launch_bounds__(1024) void k_scan1(const int* __restrict__ counts,
                                                int* __restrict__ offsets,
                                                float* __restrict__ deg_inv,
                                                int* __restrict__ bsum) {
    __shared__ int wsum[16];
    int tid = threadIdx.x, lane = tid & 63, wid = tid >> 6;
    int i = blockIdx.x * 1024 + tid;
    int v = (i < N_NODES) ? counts[i] : 0;
    if (i < N_NODES) deg_inv[i] = rsqrtf((float)v + 1.0f);
    int x = v;
    #pragma unroll
    for (int off = 1; off < 64; off <<= 1) {
        int y = __shfl_up(x, off, 64);
        if (lane >= off) x += y;
    }
    if (lane == 63) wsum[wid] = x;
    __syncthreads();
    if (wid == 0 && lane < 16) {
        int w = wsum[lane];
        #pragma unroll
        for (int off = 1; off < 16; off <<= 1) {
            int y = __shfl_up(w, off, 16);
            if (lane >= off) w += y;
        }
        wsum[lane] = w;
    }
    __syncthreads();
    int wbase = (wid > 0) ? wsum[wid - 1] : 0;
    int incl = x + wbase;
    if (i < N_NODES) offsets[i + 1] = incl;
    if (tid == 1023) bsum[blockIdx.x] = incl;
}

// add block-prefix; block 0 thread 0 writes offsets[0]
__global__ __launch_bounds__(1024) void k_scan2(int* __restrict__ offsets,
                                                const int* __restrict__ bsum) {
    __shared__ int s_pre;
    int b = blockIdx.x, tid = threadIdx.x;
    if (tid == 0) {
        int p = 0;
        for (int j = 0; j < b; j++) p += bsum[j];
        s_pre = p;
        if (b == 0) offsets[0] = 0;
    }
    __syncthreads();
    int i = b * 1024 + tid;
    if (i < N_NODES) offsets[i + 1] += s_pre;
}

__global__ void k_scatter(const int* __restrict__ ei, const int* __restrict__ offsets,
                          int* __restrict__ cursor, const float* __restrict__ deg_inv,
                          int2* __restrict__ csr) {
    int e = blockIdx.x * blockDim.x + threadIdx.x;
    if (e >= N_EDGES) return;
    int s = ei[e];
    int d = ei[N_EDGES + e];
    int pos = offsets[d] + atomicAdd(&cursor[d], 1);
    csr[pos] = make_int2(s, __float_as_int(deg_inv[s] * deg_inv[d]));
}

// ---------------- GEMM: H = f(X) @ W, f = optional BN+ReLU (stats fused) --------
#define GEMM_BM 64
__global__ __launch_bounds__(256) void k_gemm(const float* __restrict__ X,
                                              const float* __restrict__ Wl,
                                              float* __restrict__ H,
                                              const float* __restrict__ gstats, // [2][128] or null
                                              const float* __restrict__ gamma,
                                              const float* __restrict__ beta,
                                              int do_bn_relu) {
    __shared__ float xs[GEMM_BM][D];   // 32 KB
    __shared__ float s_sc[D], s_sh[D];
    int tid = threadIdx.x;
    if (tid < D) {
        if (do_bn_relu) {
            const float invN = 1.0f / (float)N_NODES;
            float mu = gstats[tid] * invN;
            float var = gstats[D + tid] * invN - mu * mu;
            float sc = gamma[tid] * rsqrtf(var + BN_EPS);
            s_sc[tid] = sc;
            s_sh[tid] = beta[tid] - mu * sc;
        } else {
            s_sc[tid] = 1.0f;
            s_sh[tid] = 0.0f;
        }
    }
    __syncthreads();
    int row0 = blockIdx.x * GEMM_BM;
    #pragma unroll
    for (int j = 0; j < 8; j++) {
        int idx = tid + j * 256;       // float4 index (2048 total)
        int r = idx >> 5;
        int c4 = (idx & 31) * 4;
        float4 v;
        int gr = row0 + r;
        if (gr < N_NODES) v = *(const float4*)&X[(long)gr * D + c4];
        else v = make_float4(0.f, 0.f, 0.f, 0.f);
        if (do_bn_relu) {
            v.x = fmaxf(v.x * s_sc[c4 + 0] + s_sh[c4 + 0], 0.f);
            v.y = fmaxf(v.y * s_sc[c4 + 1] + s_sh[c4 + 1], 0.f);
            v.z = fmaxf(v.z * s_sc[c4 + 2] + s_sh[c4 + 2], 0.f);
            v.w = fmaxf(v.w * s_sc[c4 + 3] + s_sh[c4 + 3], 0.f);
        }
        *(float4*)&xs[r][c4] = v;
    }
    __syncthreads();
    int tc = tid & 31, tr = tid >> 5;
    int r0 = tr * 8, c0 = tc * 4;
    float acc[8][4] = {};
    #pragma unroll 4
    for (int k = 0; k < D; k++) {
        float4 w = *(const float4*)&Wl[k * D + c0];
        #pragma unroll
        for (int i = 0; i < 8; i++) {
            float xv = xs[r0 + i][k];
            acc[i][0] += xv * w.x;
            acc[i][1] += xv * w.y;
            acc[i][2] += xv * w.z;
            acc[i][3] += xv * w.w;
        }
    }
    #pragma unroll
    for (int i = 0; i < 8; i++) {
        int gr = row0 + r0 + i;
        if (gr < N_NODES) {
            float4 o = make_float4(acc[i][0], acc[i][1], acc[i][2], acc[i][3]);
            *(float4*)&H[(long)gr * D + c0] = o;
        }
    }
}

// ---------------- Aggregation + bias + BN-stat accumulation ----------------
#define AGG_NPW 2
#define AGG_WAVES 4
#define AGG_NPB (AGG_NPW * AGG_WAVES)
__global__ __launch_bounds__(256) void k_agg(const float* __restrict__ H,
                                             const float* __restrict__ deg_inv,
                                             const int* __restrict__ offsets,
                                             const int2* __restrict__ csr,
                                             const float* __restrict__ bias,
                                             float* __restrict__ Xout,
                                             float* __restrict__ gsum,
                                             float* __restrict__ gsq) {
    __shared__ float s_sum[D], s_sq[D];
    int tid = threadIdx.x, lane = tid & 63, wid = tid >> 6;
    if (tid < D) { s_sum[tid] = 0.f; s_sq[tid] = 0.f; }
    __syncthreads();
    int c = lane * 2;
    float b0 = bias[c], b1 = bias[c + 1];
    float ps0 = 0.f, ps1 = 0.f, pq0 = 0.f, pq1 = 0.f;
    int nodeBase = blockIdx.x * AGG_NPB + wid * AGG_NPW;
    for (int t = 0; t < AGG_NPW; t++) {
        int n = nodeBase + t;
        if (n >= N_NODES) break;
        float di = deg_inv[n];
        float2 hv = *(const float2*)&H[(long)n * D + c];
        float self = di * di;
        float a0 = hv.x * self + b0;
        float a1 = hv.y * self + b1;
        int e = offsets[n], e1 = offsets[n + 1];
        // 4 independent row-gathers in flight
        for (; e + 4 <= e1; e += 4) {
            int2 p0 = csr[e + 0];
            int2 p1 = csr[e + 1];
            int2 p2 = csr[e + 2];
            int2 p3 = csr[e + 3];
            float2 h0 = *(const float2*)&H[(long)p0.x * D + c];
            float2 h1 = *(const float2*)&H[(long)p1.x * D + c];
            float2 h2 = *(const float2*)&H[(long)p2.x * D + c];
            float2 h3 = *(const float2*)&H[(long)p3.x * D + c];
            float w0 = __int_as_float(p0.y), w1 = __int_as_float(p1.y);
            float w2 = __int_as_float(p2.y), w3 = __int_as_float(p3.y);
            a0 += h0.x * w0; a1 += h0.y * w0;
            a0 += h1.x * w1; a1 += h1.y * w1;
            a0 += h2.x * w2; a1 += h2.y * w2;
            a0 += h3.x * w3; a1 += h3.y * w3;
        }
        for (; e < e1; e++) {
            int2 p = csr[e];
            float w = __int_as_float(p.y);
            float2 hs = *(const float2*)&H[(long)p.x * D + c];
            a0 += hs.x * w;
            a1 += hs.y * w;
        }
        *(float2*)&Xout[(long)n * D + c] = make_float2(a0, a1);
        ps0 += a0; ps1 += a1;
        pq0 += a0 * a0; pq1 += a1 * a1;
    }
    atomicAdd(&s_sum[c], ps0);
    atomicAdd(&s_sum[c + 1], ps1);
    atomicAdd(&s_sq[c], pq0);
    atomicAdd(&s_sq[c + 1], pq1);
    __syncthreads();
    if (tid < D) {
        atomicAdd(&gsum[tid], s_sum[tid]);
        atomicAdd(&gsq[tid], s_sq[tid]);
    }
}

// ---------------- Fused final BN+ReLU + mean-pool + classifier ----------------
__global__ __launch_bounds__(256) void k_poolcls(const float* __restrict__ X,
                                                 const int* __restrict__ batch,
                                                 const float* __restrict__ gstats, // [2][128]
                                                 const float* __restrict__ gamma,
                                                 const float* __restrict__ beta,
                                                 const float* __restrict__ Wc,
                                                 const float* __restrict__ bc,
                                                 float* __restrict__ out) {
    __shared__ float s_pool[D];
    __shared__ int s_lo, s_hi;
    int g = blockIdx.x, tid = threadIdx.x;
    if (tid == 0) {
        int lo = 0, hi = N_NODES;
        while (lo < hi) { int m = (lo + hi) >> 1; if (batch[m] < g) lo = m + 1; else hi = m; }
        s_lo = lo;
        hi = N_NODES;
        while (lo < hi) { int m = (lo + hi) >> 1; if (batch[m] < g + 1) lo = m + 1; else hi = m; }
        s_hi = lo;
    }
    if (tid < D) s_pool[tid] = 0.f;
    __syncthreads();
    int lo = s_lo, hi = s_hi;
    int c4 = (tid & 31) * 4, q = tid >> 5;   // 8 row-groups in flight
    const float invN = 1.0f / (float)N_NODES;
    float sc[4], sh[4];
    #pragma unroll
    for (int j = 0; j < 4; j++) {
        float mu = gstats[c4 + j] * invN;
        float var = gstats[D + c4 + j] * invN - mu * mu;
        sc[j] = gamma[c4 + j] * rsqrtf(var + BN_EPS);
        sh[j] = beta[c4 + j] - mu * sc[j];
    }
    float acc[4] = {0.f, 0.f, 0.f, 0.f};
    for (int n = lo + q; n < hi; n += 8) {
        float4 v = *(const float4*)&X[(long)n * D + c4];
        acc[0] += fmaxf(v.x * sc[0] + sh[0], 0.f);
        acc[1] += fmaxf(v.y * sc[1] + sh[1], 0.f);
        acc[2] += fmaxf(v.z * sc[2] + sh[2], 0.f);
        acc[3] += fmaxf(v.w * sc[3] + sh[3], 0.f);
    }
    #pragma unroll
    for (int j = 0; j < 4; j++) atomicAdd(&s_pool[c4 + j], acc[j]);
    __syncthreads();
    if (tid < N_CLASSES) {
        float cnt = fmaxf((float)(hi - lo), 1.0f);
        float r = 0.f;
        #pragma unroll 16
        for (int k = 0; k < D; k++) r += s_pool[k] * Wc[k * N_CLASSES + tid];
        out[(long)g * N_CLASSES + tid] = r / cnt + bc[tid];
    }
}

// ---------------- launch ----------------
extern "C" void kernel_launch(void* const* d_in, const int* in_sizes, int n_in,
                              void* d_out, int out_size, void* d_ws, size_t ws_size,
                              hipStream_t stream) {
    const float* x     = (const float*)d_in[0];
    const float* W     = (const float*)d_in[1];   // [4,128,128]
    const float* b     = (const float*)d_in[2];   // [4,128]
    const float* gamma = (const float*)d_in[3];
    const float* beta  = (const float*)d_in[4];
    const float* Wc    = (const float*)d_in[5];
    const float* bc    = (const float*)d_in[6];
    const int*   ei    = (const int*)d_in[7];     // [2, E]
    const int*   batch = (const int*)d_in[8];
    float* out = (float*)d_out;

    char* ws = (char*)d_ws;
    size_t off = 0;
    auto alloc = [&](size_t bytes) {
        void* p = ws + off;
        off += (bytes + 255) & ~(size_t)255;
        return p;
    };
    float* cur_x    = (float*)alloc((size_t)N_NODES * D * 4);
    float* h        = (float*)alloc((size_t)N_NODES * D * 4);
    float* deg_inv  = (float*)alloc(N_NODES * 4);
    int*   offsets  = (int*)alloc((N_NODES + 1) * 4);
    int2*  csr      = (int2*)alloc((size_t)N_EDGES * 8);
    int*   bsum     = (int*)alloc(SCAN_BLOCKS * 4);
    // --- zeroed region (single memset): counts | cursor | gstats[4][2][128] ---
    size_t zero_begin = off;
    int*   counts   = (int*)alloc(N_NODES * 4);
    int*   cursor   = (int*)alloc(N_NODES * 4);
    float* gstats   = (float*)alloc((size_t)NLAYERS * 2 * D * 4);
    size_t zero_end = off;

    hipMemsetAsync(ws + zero_begin, 0, zero_end - zero_begin, stream);

    k_hist<<<(N_EDGES + 255) / 256, 256, 0, stream>>>(ei, counts);
    k_scan1<<<SCAN_BLOCKS, 1024, 0, stream>>>(counts, offsets, deg_inv, bsum);
    k_scan2<<<SCAN_BLOCKS, 1024, 0, stream>>>(offsets, bsum);
    k_scatter<<<(N_EDGES + 255) / 256, 256, 0, stream>>>(ei, offsets, cursor, deg_inv, csr);

    const int gemm_grid = (N_NODES + GEMM_BM - 1) / GEMM_BM;
    const int agg_grid = (N_NODES + AGG_NPB - 1) / AGG_NPB;
    for (int l = 0; l < NLAYERS; l++) {
        const float* Xin = (l == 0) ? x : cur_x;
        const float* st  = (l == 0) ? nullptr : gstats + (size_t)(l - 1) * 2 * D;
        const float* gm  = gamma + (size_t)((l == 0) ? 0 : l - 1) * D;
        const float* bt  = beta + (size_t)((l == 0) ? 0 : l - 1) * D;
        k_gemm<<<gemm_grid, 256, 0, stream>>>(Xin, W + (size_t)l * D * D, h,
                                              st, gm, bt, (l == 0) ? 0 : 1);
        float* gs = gstats + (size_t)l * 2 * D;
        k_agg<<<agg_grid, 256, 0, stream>>>(h, deg_inv, offsets, csr,
                                            b + (size_t)l * D, cur_x, gs, gs + D);
    }

    k_poolcls<<<N_GRAPHS, 256, 0, stream>>>(cur_x, batch,
                                            gstats + (size_t)(NLAYERS - 1) * 2 * D,
                                            gamma + (size_t)(NLAYERS - 1) * D,
                                            beta + (size_t)(NLAYERS - 1) * D,
                                            Wc, bc, out);
}

// Round 10
// 633.856 us; speedup vs baseline: 1.6691x; 1.6691x over previous
//
#include <hip/hip_runtime.h>
#include <hip/hip_bf16.h>

#define N_NODES 50000
#define N_EDGES 800000
#define D 128
#define NLAYERS 4
#define N_GRAPHS 512
#define N_CLASSES 10
#define BN_EPS 1e-5f
#define SCAN_BLOCKS ((N_NODES + 1023) / 1024)
#define NPART 64   // BN-stat partial buffers (atomic contention: nblocks/NPART per addr)

// ---------------- CSR build ----------------
__global__ void k_hist(const int* __restrict__ ei, int* __restrict__ counts) {
    int e = blockIdx.x * blockDim.x + threadIdx.x;
    if (e < N_EDGES) atomicAdd(&counts[ei[N_EDGES + e]], 1);
}

// per-1024-block inclusive scan; also deg_inv = rsqrt(count+1)
__global__ __launch_bounds__(1024) void k_scan1(const int* __restrict__ counts,
                                                int* __restrict__ offsets,
                                                float* __restrict__ deg_inv,
                                                int* __restrict__ bsum) {
    __shared__ int wsum[16];
    int tid = threadIdx.x, lane = tid & 63, wid = tid >> 6;
    int i = blockIdx.x * 1024 + tid;
    int v = (i < N_NODES) ? counts[i] : 0;
    if (i < N_NODES) deg_inv[i] = rsqrtf((float)v + 1.0f);
    int x = v;
    #pragma unroll
    for (int off = 1; off < 64; off <<= 1) {
        int y = __shfl_up(x, off, 64);
        if (lane >= off) x += y;
    }
    if (lane == 63) wsum[wid] = x;
    __syncthreads();
    if (wid == 0 && lane < 16) {
        int w = wsum[lane];
        #pragma unroll
        for (int off = 1; off < 16; off <<= 1) {
            int y = __shfl_up(w, off, 16);
            if (lane >= off) w += y;
        }
        wsum[lane] = w;
    }
    __syncthreads();
    int wbase = (wid > 0) ? wsum[wid - 1] : 0;
    int incl = x + wbase;
    if (i < N_NODES) offsets[i + 1] = incl;
    if (tid == 1023) bsum[blockIdx.x] = incl;
}

// add block-prefix; block 0 thread 0 writes offsets[0]
__global__ __launch_bounds__(1024) void k_scan2(int* __restrict__ offsets,
                                                const int* __restrict__ bsum) {
    __shared__ int s_pre;
    int b = blockIdx.x, tid = threadIdx.x;
    if (tid == 0) {
        int p = 0;
        for (int j = 0; j < b; j++) p += bsum[j];
        s_pre = p;
        if (b == 0) offsets[0] = 0;
    }
    __syncthreads();
    int i = b * 1024 + tid;
    if (i < N_NODES) offsets[i + 1] += s_pre;
}

__global__ void k_scatter(const int* __restrict__ ei, const int* __restrict__ offsets,
                          int* __restrict__ cursor, const float* __restrict__ deg_inv,
                          int2* __restrict__ csr) {
    int e = blockIdx.x * blockDim.x + threadIdx.x;
    if (e >= N_EDGES) return;
    int s = ei[e];
    int d = ei[N_EDGES + e];
    int pos = offsets[d] + atomicAdd(&cursor[d], 1);
    csr[pos] = make_int2(s, __float_as_int(deg_inv[s] * deg_inv[d]));
}

// ---------------- GEMM: H = f(X) @ W, f = optional BN+ReLU ----------------
// gstats = [NPART][2][D] partials from previous k_agg (or null for layer 0)
#define GEMM_BM 64
__global__ __launch_bounds__(256) void k_gemm(const float* __restrict__ X,
                                              const float* __restrict__ Wl,
                                              float* __restrict__ H,
                                              const float* __restrict__ gstats,
                                              const float* __restrict__ gamma,
                                              const float* __restrict__ beta,
                                              int do_bn_relu) {
    __shared__ float xs[GEMM_BM][D];   // 32 KB
    __shared__ float s_sc[D], s_sh[D];
    int tid = threadIdx.x;
    if (tid < D) {
        if (do_bn_relu) {
            float s = 0.f, q = 0.f;
            #pragma unroll 8
            for (int p = 0; p < NPART; p++) {
                s += gstats[p * 2 * D + tid];
                q += gstats[p * 2 * D + D + tid];
            }
            const float invN = 1.0f / (float)N_NODES;
            float mu = s * invN;
            float var = q * invN - mu * mu;
            float sc = gamma[tid] * rsqrtf(var + BN_EPS);
            s_sc[tid] = sc;
            s_sh[tid] = beta[tid] - mu * sc;
        } else {
            s_sc[tid] = 1.0f;
            s_sh[tid] = 0.0f;
        }
    }
    __syncthreads();
    int row0 = blockIdx.x * GEMM_BM;
    #pragma unroll
    for (int j = 0; j < 8; j++) {
        int idx = tid + j * 256;       // float4 index (2048 total)
        int r = idx >> 5;
        int c4 = (idx & 31) * 4;
        float4 v;
        int gr = row0 + r;
        if (gr < N_NODES) v = *(const float4*)&X[(long)gr * D + c4];
        else v = make_float4(0.f, 0.f, 0.f, 0.f);
        if (do_bn_relu) {
            v.x = fmaxf(v.x * s_sc[c4 + 0] + s_sh[c4 + 0], 0.f);
            v.y = fmaxf(v.y * s_sc[c4 + 1] + s_sh[c4 + 1], 0.f);
            v.z = fmaxf(v.z * s_sc[c4 + 2] + s_sh[c4 + 2], 0.f);
            v.w = fmaxf(v.w * s_sc[c4 + 3] + s_sh[c4 + 3], 0.f);
        }
        *(float4*)&xs[r][c4] = v;
    }
    __syncthreads();
    int tc = tid & 31, tr = tid >> 5;
    int r0 = tr * 8, c0 = tc * 4;
    float acc[8][4] = {};
    #pragma unroll 4
    for (int k = 0; k < D; k++) {
        float4 w = *(const float4*)&Wl[k * D + c0];
        #pragma unroll
        for (int i = 0; i < 8; i++) {
            float xv = xs[r0 + i][k];
            acc[i][0] += xv * w.x;
            acc[i][1] += xv * w.y;
            acc[i][2] += xv * w.z;
            acc[i][3] += xv * w.w;
        }
    }
    #pragma unroll
    for (int i = 0; i < 8; i++) {
        int gr = row0 + r0 + i;
        if (gr < N_NODES) {
            float4 o = make_float4(acc[i][0], acc[i][1], acc[i][2], acc[i][3]);
            *(float4*)&H[(long)gr * D + c0] = o;
        }
    }
}

// ---------------- Aggregation + bias + BN-stat partials ----------------
#define AGG_NPW 2
#define AGG_WAVES 4
#define AGG_NPB (AGG_NPW * AGG_WAVES)
__global__ __launch_bounds__(256) void k_agg(const float* __restrict__ H,
                                             const float* __restrict__ deg_inv,
                                             const int* __restrict__ offsets,
                                             const int2* __restrict__ csr,
                                             const float* __restrict__ bias,
                                             float* __restrict__ Xout,
                                             float* __restrict__ gstats) { // [NPART][2][D]
    __shared__ float s_sum[D], s_sq[D];
    int tid = threadIdx.x, lane = tid & 63, wid = tid >> 6;
    if (tid < D) { s_sum[tid] = 0.f; s_sq[tid] = 0.f; }
    __syncthreads();
    int c = lane * 2;
    float b0 = bias[c], b1 = bias[c + 1];
    float ps0 = 0.f, ps1 = 0.f, pq0 = 0.f, pq1 = 0.f;
    int nodeBase = blockIdx.x * AGG_NPB + wid * AGG_NPW;
    for (int t = 0; t < AGG_NPW; t++) {
        int n = nodeBase + t;
        if (n >= N_NODES) break;
        float di = deg_inv[n];
        float2 hv = *(const float2*)&H[(long)n * D + c];
        float self = di * di;
        float a0 = hv.x * self + b0;
        float a1 = hv.y * self + b1;
        int e = offsets[n], e1 = offsets[n + 1];
        // 4 independent row-gathers in flight
        for (; e + 4 <= e1; e += 4) {
            int2 p0 = csr[e + 0];
            int2 p1 = csr[e + 1];
            int2 p2 = csr[e + 2];
            int2 p3 = csr[e + 3];
            float2 h0 = *(const float2*)&H[(long)p0.x * D + c];
            float2 h1 = *(const float2*)&H[(long)p1.x * D + c];
            float2 h2 = *(const float2*)&H[(long)p2.x * D + c];
            float2 h3 = *(const float2*)&H[(long)p3.x * D + c];
            float w0 = __int_as_float(p0.y), w1 = __int_as_float(p1.y);
            float w2 = __int_as_float(p2.y), w3 = __int_as_float(p3.y);
            a0 += h0.x * w0; a1 += h0.y * w0;
            a0 += h1.x * w1; a1 += h1.y * w1;
            a0 += h2.x * w2; a1 += h2.y * w2;
            a0 += h3.x * w3; a1 += h3.y * w3;
        }
        for (; e < e1; e++) {
            int2 p = csr[e];
            float w = __int_as_float(p.y);
            float2 hs = *(const float2*)&H[(long)p.x * D + c];
            a0 += hs.x * w;
            a1 += hs.y * w;
        }
        *(float2*)&Xout[(long)n * D + c] = make_float2(a0, a1);
        ps0 += a0; ps1 += a1;
        pq0 += a0 * a0; pq1 += a1 * a1;
    }
    atomicAdd(&s_sum[c], ps0);
    atomicAdd(&s_sum[c + 1], ps1);
    atomicAdd(&s_sq[c], pq0);
    atomicAdd(&s_sq[c + 1], pq1);
    __syncthreads();
    if (tid < D) {
        int part = blockIdx.x & (NPART - 1);
        float* gp = gstats + (size_t)part * 2 * D;
        atomicAdd(&gp[tid], s_sum[tid]);
        atomicAdd(&gp[D + tid], s_sq[tid]);
    }
}

// ---------------- Fused final BN+ReLU + mean-pool + classifier ----------------
__global__ __launch_bounds__(256) void k_poolcls(const float* __restrict__ X,
                                                 const int* __restrict__ batch,
                                                 const float* __restrict__ gstats, // [NPART][2][D]
                                                 const float* __restrict__ gamma,
                                                 const float* __restrict__ beta,
                                                 const float* __restrict__ Wc,
                                                 const float* __restrict__ bc,
                                                 float* __restrict__ out) {
    __shared__ float s_pool[D];
    __shared__ float s_sc[D], s_sh[D];
    __shared__ int s_lo, s_hi;
    int g = blockIdx.x, tid = threadIdx.x;
    if (tid == 0) {
        int lo = 0, hi = N_NODES;
        while (lo < hi) { int m = (lo + hi) >> 1; if (batch[m] < g) lo = m + 1; else hi = m; }
        s_lo = lo;
        hi = N_NODES;
        while (lo < hi) { int m = (lo + hi) >> 1; if (batch[m] < g + 1) lo = m + 1; else hi = m; }
        s_hi = lo;
    }
    if (tid < D) {
        float s = 0.f, q = 0.f;
        #pragma unroll 8
        for (int p = 0; p < NPART; p++) {
            s += gstats[p * 2 * D + tid];
            q += gstats[p * 2 * D + D + tid];
        }
        const float invN = 1.0f / (float)N_NODES;
        float mu = s * invN;
        float var = q * invN - mu * mu;
        float sc = gamma[tid] * rsqrtf(var + BN_EPS);
        s_sc[tid] = sc;
        s_sh[tid] = beta[tid] - mu * sc;
        s_pool[tid] = 0.f;
    }
    __syncthreads();
    int lo = s_lo, hi = s_hi;
    int c4 = (tid & 31) * 4, q = tid >> 5;   // 8 row-groups in flight
    float sc[4], sh[4];
    #pragma unroll
    for (int j = 0; j < 4; j++) { sc[j] = s_sc[c4 + j]; sh[j] = s_sh[c4 + j]; }
    float acc[4] = {0.f, 0.f, 0.f, 0.f};
    for (int n = lo + q; n < hi; n += 8) {
        float4 v = *(const float4*)&X[(long)n * D + c4];
        acc[0] += fmaxf(v.x * sc[0] + sh[0], 0.f);
        acc[1] += fmaxf(v.y * sc[1] + sh[1], 0.f);
        acc[2] += fmaxf(v.z * sc[2] + sh[2], 0.f);
        acc[3] += fmaxf(v.w * sc[3] + sh[3], 0.f);
    }
    #pragma unroll
    for (int j = 0; j < 4; j++) atomicAdd(&s_pool[c4 + j], acc[j]);
    __syncthreads();
    if (tid < N_CLASSES) {
        float cnt = fmaxf((float)(hi - lo), 1.0f);
        float r = 0.f;
        #pragma unroll 16
        for (int k = 0; k < D; k++) r += s_pool[k] * Wc[k * N_CLASSES + tid];
        out[(long)g * N_CLASSES + tid] = r / cnt + bc[tid];
    }
}

// ---------------- launch ----------------
extern "C" void kernel_launch(void* const* d_in, const int* in_sizes, int n_in,
                              void* d_out, int out_size, void* d_ws, size_t ws_size,
                              hipStream_t stream) {
    const float* x     = (const float*)d_in[0];
    const float* W     = (const float*)d_in[1];   // [4,128,128]
    const float* b     = (const float*)d_in[2];   // [4,128]
    const float* gamma = (const float*)d_in[3];
    const float* beta  = (const float*)d_in[4];
    const float* Wc    = (const float*)d_in[5];
    const float* bc    = (const float*)d_in[6];
    const int*   ei    = (const int*)d_in[7];     // [2, E]
    const int*   batch = (const int*)d_in[8];
    float* out = (float*)d_out;

    char* ws = (char*)d_ws;
    size_t off = 0;
    auto alloc = [&](size_t bytes) {
        void* p = ws + off;
        off += (bytes + 255) & ~(size_t)255;
        return p;
    };
    float* cur_x    = (float*)alloc((size_t)N_NODES * D * 4);
    float* h        = (float*)alloc((size_t)N_NODES * D * 4);
    float* deg_inv  = (float*)alloc(N_NODES * 4);
    int*   offsets  = (int*)alloc((N_NODES + 1) * 4);
    int2*  csr      = (int2*)alloc((size_t)N_EDGES * 8);
    int*   bsum     = (int*)alloc(SCAN_BLOCKS * 4);
    // --- zeroed region (one memset): counts | cursor | gstats[4][NPART][2][128] ---
    size_t zero_begin = off;
    int*   counts   = (int*)alloc(N_NODES * 4);
    int*   cursor   = (int*)alloc(N_NODES * 4);
    float* gstats   = (float*)alloc((size_t)NLAYERS * NPART * 2 * D * 4);
    size_t zero_end = off;

    hipMemsetAsync(ws + zero_begin, 0, zero_end - zero_begin, stream);

    k_hist<<<(N_EDGES + 255) / 256, 256, 0, stream>>>(ei, counts);
    k_scan1<<<SCAN_BLOCKS, 1024, 0, stream>>>(counts, offsets, deg_inv, bsum);
    k_scan2<<<SCAN_BLOCKS, 1024, 0, stream>>>(offsets, bsum);
    k_scatter<<<(N_EDGES + 255) / 256, 256, 0, stream>>>(ei, offsets, cursor, deg_inv, csr);

    const int gemm_grid = (N_NODES + GEMM_BM - 1) / GEMM_BM;
    const int agg_grid = (N_NODES + AGG_NPB - 1) / AGG_NPB;
    const size_t lstat = (size_t)NPART * 2 * D;
    for (int l = 0; l < NLAYERS; l++) {
        const float* Xin = (l == 0) ? x : cur_x;
        const float* st  = (l == 0) ? nullptr : gstats + (size_t)(l - 1) * lstat;
        const float* gm  = gamma + (size_t)((l == 0) ? 0 : l - 1) * D;
        const float* bt  = beta + (size_t)((l == 0) ? 0 : l - 1) * D;
        k_gemm<<<gemm_grid, 256, 0, stream>>>(Xin, W + (size_t)l * D * D, h,
                                              st, gm, bt, (l == 0) ? 0 : 1);
        k_agg<<<agg_grid, 256, 0, stream>>>(h, deg_inv, offsets, csr,
                                            b + (size_t)l * D, cur_x,
                                            gstats + (size_t)l * lstat);
    }

    k_poolcls<<<N_GRAPHS, 256, 0, stream>>>(cur_x, batch,
                                            gstats + (size_t)(NLAYERS - 1) * lstat,
                                            gamma + (size_t)(NLAYERS - 1) * D,
                                            beta + (size_t)(NLAYERS - 1) * D,
                                            Wc, bc, out);
}